// Round 8
// baseline (943.853 us; speedup 1.0000x reference)
//
#include <hip/hip_runtime.h>

#define L_LEN 39904
#define TTB 32
#define NT32 1247
#define NT 624
#define RCH 120
#define SCH 240
#define CMEL 80
#define NQO 256
#define NBLK 16
#define KUP 800

typedef unsigned short u16;
typedef __attribute__((ext_vector_type(8))) short short8;
typedef __attribute__((ext_vector_type(4))) float f32x4;

#define MFMA(a, b, c) __builtin_amdgcn_mfma_f32_16x16x32_bf16((a), (b), (c), 0, 0, 0)

__device__ __forceinline__ u16 f2bf(float f) {
    unsigned u = __float_as_uint(f);
    u += 0x7FFFu + ((u >> 16) & 1u);
    return (u16)(u >> 16);
}
__device__ __forceinline__ unsigned pack2(float a, float b) {
    return (unsigned)f2bf(a) | ((unsigned)f2bf(b) << 16);
}
__device__ __forceinline__ float b16tof(u16 h) {
    return __uint_as_float((unsigned)h << 16);
}
// fast gating: tanh(a)*sigmoid(b) via v_exp + v_rcp (err ~1e-7, << bf16 noise)
__device__ __forceinline__ float gate(float a, float b) {
    float ea = __expf(2.f * a);
    float th = 1.f - 2.f * __builtin_amdgcn_rcpf(ea + 1.f);
    float sg = __builtin_amdgcn_rcpf(1.f + __expf(-b));
    return th * sg;
}

// ---- ws layout (byte offsets, all 256-aligned) ----
constexpr size_t O_CONDT = 0;                       // [L][88] bf16
constexpr size_t O_RESA  = O_CONDT + 7023104;       // [L][120] f32
constexpr size_t O_RESB  = O_RESA + 19153920;
constexpr size_t O_SKIP  = O_RESB + 19153920;       // [L][240] bf16
constexpr size_t O_ZFRAG = O_SKIP + 19153920;
constexpr size_t O_SKF   = O_ZFRAG + 2621440;
constexpr size_t O_RF    = O_SKF + 1048576;
constexpr size_t O_H1F   = O_RF + 524288;
constexpr size_t O_H2F   = O_H1F + 131072;
constexpr size_t O_UPF   = O_H2F + 131072;
constexpr size_t O_ZB    = O_UPF + 13107200;
constexpr size_t O_SKB   = O_ZB + 16384;

// ================= prep kernels =================
__global__ void k_prep_zfrag(const float* __restrict__ bc_w, const float* __restrict__ bq_w,
                             u16* __restrict__ dst) {
    int i = blockIdx.x * 256 + threadIdx.x;
    if (i >= NBLK * 10 * 16 * 512) return;
    int jj = i & 7, lane = (i >> 3) & 63, mt = (i >> 9) & 15;
    int rest = i >> 13, ks = rest % 10, blk = rest / 10;
    int m = mt * 16 + (lane & 15);
    int k = ks * 32 + ((lane >> 4) << 3) + jj;
    float v = 0.f;
    if (m < 240) {
        int o = (m & 1) ? (m >> 1) + 120 : (m >> 1);
        if (k < 120)       v = bc_w[((size_t)(blk * 240 + o) * 120 + k) * 2 + 0];
        else if (k < 240)  v = bc_w[((size_t)(blk * 240 + o) * 120 + (k - 120)) * 2 + 1];
        else               v = bq_w[(size_t)(blk * 240 + o) * 80 + (k - 240)];
    }
    dst[i] = f2bf(v);
}
__global__ void k_prep_skfrag(const float* __restrict__ bs_w, u16* __restrict__ dst) {
    int i = blockIdx.x * 256 + threadIdx.x;
    if (i >= NBLK * 4 * 16 * 512) return;
    int jj = i & 7, lane = (i >> 3) & 63, mt = (i >> 9) & 15;
    int rest = i >> 13, ks = rest & 3, blk = rest >> 2;
    int m = mt * 16 + (lane & 15);
    int k = ks * 32 + ((lane >> 4) << 3) + jj;
    float v = (m < 240 && k < 120) ? bs_w[(size_t)(blk * 240 + m) * 120 + k] : 0.f;
    dst[i] = f2bf(v);
}
__global__ void k_prep_rfrag(const float* __restrict__ br_w, u16* __restrict__ dst) {
    int i = blockIdx.x * 256 + threadIdx.x;
    if (i >= NBLK * 4 * 8 * 512) return;
    int jj = i & 7, lane = (i >> 3) & 63, mt = (i >> 9) & 7;
    int rest = i >> 12, ks = rest & 3, blk = rest >> 2;
    int m = mt * 16 + (lane & 15);
    int k = ks * 32 + ((lane >> 4) << 3) + jj;
    float v = (m < 120 && k < 120) ? br_w[(size_t)(blk * 120 + m) * 120 + k] : 0.f;
    dst[i] = f2bf(v);
}
__global__ void k_prep_h1frag(const float* __restrict__ h1_w, u16* __restrict__ dst) {
    int i = blockIdx.x * 256 + threadIdx.x;
    if (i >= 8 * 16 * 512) return;
    int jj = i & 7, lane = (i >> 3) & 63, mt = (i >> 9) & 15, ks = i >> 13;
    int m = mt * 16 + (lane & 15);
    int k = ks * 32 + ((lane >> 4) << 3) + jj;
    float v = (k < 240) ? h1_w[(size_t)m * 240 + k] : 0.f;
    dst[i] = f2bf(v);
}
__global__ void k_prep_h2frag(const float* __restrict__ h2_w, u16* __restrict__ dst) {
    int i = blockIdx.x * 256 + threadIdx.x;
    if (i >= 8 * 16 * 512) return;
    int jj = i & 7, lane = (i >> 3) & 63, mt = (i >> 9) & 15, ks = i >> 13;
    int m = mt * 16 + (lane & 15);
    int k = ks * 32 + ((lane >> 4) << 3) + jj;
    dst[i] = f2bf(h2_w[(size_t)m * 256 + k]);
}
__global__ void k_prep_upfrag(const float* __restrict__ up_w, u16* __restrict__ dst) {
    int i = blockIdx.x * 256 + threadIdx.x;
    if (i >= 256 * 10 * 5 * 512) return;
    int jj = i & 7, lane = (i >> 3) & 63;
    int rest = i >> 9;
    int mt = rest % 5; rest /= 5;
    int ks = rest % 10; int p = rest / 10;
    int m = mt * 16 + (lane & 15);
    int k = ks * 32 + ((lane >> 4) << 3) + jj;
    int c = k >> 2, j = k & 3;
    int r = (256 - ((p + 1) & 255)) & 255;
    int kk = r + 256 * j;
    float v = (m < 80 && kk < KUP) ? up_w[((size_t)m * 80 + c) * KUP + kk] : 0.f;
    dst[i] = f2bf(v);
}
__global__ void k_prep_zbias(const float* __restrict__ bc_b, const float* __restrict__ bq_b,
                             float* __restrict__ dst) {
    int i = blockIdx.x * 256 + threadIdx.x;
    if (i >= NBLK * 256) return;
    int m = i & 255, blk = i >> 8;
    float v = 0.f;
    if (m < 240) {
        int o = (m & 1) ? (m >> 1) + 120 : (m >> 1);
        v = bc_b[blk * 240 + o] + bq_b[blk * 240 + o];
    }
    dst[i] = v;
}
__global__ void k_prep_skbias(const float* __restrict__ bs_b, float* __restrict__ dst) {
    int i = blockIdx.x * 256 + threadIdx.x;
    if (i >= NBLK * 240) return;
    dst[i] = bs_b[i];
}
__global__ void k_res_initT(const float* __restrict__ wav, const float* __restrict__ in_w,
                            const float* __restrict__ in_b, float* __restrict__ resT) {
    int i = blockIdx.x * 256 + threadIdx.x;
    if (i >= L_LEN * RCH) return;
    int t = i / RCH, c = i % RCH;
    resT[i] = wav[t] * in_w[c] + in_b[c];
}

// ================= upsample (MFMA, per phase p) =================
__global__ __launch_bounds__(256) void k_up(const float* __restrict__ mel,
        const u16* __restrict__ upf, const float* __restrict__ up_b,
        u16* __restrict__ condT) {
    __shared__ u16 s_ms[64 * 328];
    const int tid = threadIdx.x, l = tid & 63, w = tid >> 6;
    const int quad = l >> 4, tloc = l & 15;
    const int p = blockIdx.x, s0 = blockIdx.y * 64;
    for (int rr = 0; rr < 16; rr++) {
        int tt = w + 4 * rr;
        int sg = s0 + tt;
        #pragma unroll
        for (int base = 0; base < 320; base += 64) {
            int ck = base + l;
            int c = ck >> 2, j = ck & 3;
            int mi = 1 + j + sg;
            float v = (mi < 160) ? mel[c * 160 + mi] : 0.f;
            s_ms[tt * 328 + ck] = f2bf(v);
        }
    }
    __syncthreads();
    f32x4 acc[2][4];
    #pragma unroll
    for (int i = 0; i < 2; i++)
        #pragma unroll
        for (int n = 0; n < 4; n++) acc[i][n] = (f32x4){0.f, 0.f, 0.f, 0.f};
    const int nmt = (w == 0) ? 2 : 1;
    int mts[2]; mts[0] = w; mts[1] = 4;
    for (int ks = 0; ks < 10; ks++) {
        short8 b[4];
        int k0 = ks * 32 + quad * 8;
        #pragma unroll
        for (int n = 0; n < 4; n++)
            b[n] = *(const short8*)&s_ms[(n * 16 + tloc) * 328 + k0];
        const short8* ap = (const short8*)(upf) + ((size_t)p * 10 + ks) * 5 * 64;
        for (int i = 0; i < nmt; i++) {
            short8 a = ap[mts[i] * 64 + l];
            #pragma unroll
            for (int n = 0; n < 4; n++) acc[i][n] = MFMA(a, b[n], acc[i][n]);
        }
    }
    for (int i = 0; i < nmt; i++) {
        int o_base = mts[i] * 16 + quad * 4;
        float4 ub = *(const float4*)(up_b + o_base);
        float bb[4] = {ub.x, ub.y, ub.z, ub.w};
        #pragma unroll
        for (int n = 0; n < 4; n++) {
            int sg = s0 + n * 16 + tloc;
            int t = p + 256 * sg;
            if (t < L_LEN) {
                #pragma unroll
                for (int r = 0; r < 4; r++)
                    condT[(size_t)t * 88 + o_base + r] = f2bf(acc[i][n][r] + bb[r]);
            }
        }
    }
}

// ================= WaveNet block (MFMA, T=32, 512 thr / 8 waves, 4 wg/CU) =================
__global__ __launch_bounds__(512, 8) void k_block(
        const u16* __restrict__ condT, const float* __restrict__ resT_in,
        float* __restrict__ resT_out, u16* __restrict__ skipT,
        const u16* __restrict__ zfrag, const u16* __restrict__ skfrag,
        const u16* __restrict__ rfrag, const float* __restrict__ zbias,
        const float* __restrict__ skbias, const float* __restrict__ resb,
        int blk, int dil, int first) {
    __shared__ u16 s_x[TTB * 328];  // [t][k]; k: 0-119 past, 120-239 cur, 240-319 cond
    u16* s_h = s_x;                 // aliased after barrier: [t][j] stride 136
    const int tid = threadIdx.x, l = tid & 63, w = tid >> 6;  // w 0..7
    const int quad = l >> 4, tloc = l & 15;
    const int t0 = blockIdx.x * TTB;
    // prefetch first z A-frags before staging
    const short8* zap = (const short8*)(zfrag) + (size_t)blk * 10 * 16 * 64;
    short8 a_cur[2], a_nxt[2];
    #pragma unroll
    for (int i = 0; i < 2; i++) a_cur[i] = zap[(size_t)(w * 2 + i) * 64 + l];
    // ---- stage X ----
    #pragma unroll
    for (int rr = 0; rr < 4; rr++) {
        int tt = w + 8 * rr;
        int tg = t0 + tt, tp = tg - dil;
        if (l < 60) {
            float2 pv = make_float2(0.f, 0.f), cv = make_float2(0.f, 0.f);
            if (tp >= 0 && tp < L_LEN) pv = *(const float2*)(resT_in + (size_t)tp * 120 + 2 * l);
            if (tg < L_LEN)            cv = *(const float2*)(resT_in + (size_t)tg * 120 + 2 * l);
            *(unsigned*)&s_x[tt * 328 + 2 * l]       = pack2(pv.x, pv.y);
            *(unsigned*)&s_x[tt * 328 + 120 + 2 * l] = pack2(cv.x, cv.y);
        }
        if (l < 40) {
            unsigned q = 0;
            if (tg < L_LEN) q = *(const unsigned*)(condT + (size_t)tg * 88 + 2 * l);
            *(unsigned*)&s_x[tt * 328 + 240 + 2 * l] = q;
        }
    }
    __syncthreads();
    // ---- z GEMM: M=256 (2 mt/wave), K=320, N=32, prefetch pipeline ----
    f32x4 acc[2][2];
    #pragma unroll
    for (int i = 0; i < 2; i++)
        #pragma unroll
        for (int n = 0; n < 2; n++) acc[i][n] = (f32x4){0.f, 0.f, 0.f, 0.f};
    for (int ks = 0; ks < 10; ks++) {
        if (ks < 9) {
            #pragma unroll
            for (int i = 0; i < 2; i++)
                a_nxt[i] = zap[((size_t)(ks + 1) * 16 + w * 2 + i) * 64 + l];
        }
        int k0 = ks * 32 + quad * 8;
        short8 b[2];
        #pragma unroll
        for (int n = 0; n < 2; n++)
            b[n] = *(const short8*)&s_x[(n * 16 + tloc) * 328 + k0];
        #pragma unroll
        for (int i = 0; i < 2; i++)
            #pragma unroll
            for (int n = 0; n < 2; n++) acc[i][n] = MFMA(a_cur[i], b[n], acc[i][n]);
        #pragma unroll
        for (int i = 0; i < 2; i++) a_cur[i] = a_nxt[i];
    }
    // prefetch first skip/res A-frags (overlap gating VALU)
    const short8* sap = (const short8*)(skfrag) + (size_t)blk * 4 * 16 * 64;
    const short8* rap = (const short8*)(rfrag) + (size_t)blk * 4 * 8 * 64;
    short8 sa_c[2], sa_n[2], ra_c, ra_n;
    #pragma unroll
    for (int i = 0; i < 2; i++) sa_c[i] = sap[(size_t)(w * 2 + i) * 64 + l];
    ra_c = rap[(size_t)w * 64 + l];
    // prefetch skip RMW rows (bf16) and res cur rows (f32) for epilogues
    uint2 skp[2][2];
    if (!first) {
        #pragma unroll
        for (int i = 0; i < 2; i++) {
            int m_base = (w * 2 + i) * 16 + quad * 4;
            if (m_base < 240) {
                #pragma unroll
                for (int n = 0; n < 2; n++) {
                    int t = t0 + n * 16 + tloc;
                    if (t < L_LEN)
                        skp[i][n] = *(const uint2*)(skipT + (size_t)t * 240 + m_base);
                }
            }
        }
    }
    float4 rcur[2];
    {
        int m_base = w * 16 + quad * 4;
        if (m_base < 120) {
            #pragma unroll
            for (int n = 0; n < 2; n++) {
                int t = t0 + n * 16 + tloc;
                if (t < L_LEN)
                    rcur[n] = *(const float4*)(resT_in + (size_t)t * 120 + m_base);
            }
        }
    }
    // ---- gating ----
    unsigned hu[2][2];
    #pragma unroll
    for (int i = 0; i < 2; i++) {
        int m_base = (w * 2 + i) * 16 + quad * 4;
        float4 bz4 = *(const float4*)(zbias + blk * 256 + m_base);
        #pragma unroll
        for (int n = 0; n < 2; n++) {
            float h0 = gate(acc[i][n][0] + bz4.x, acc[i][n][1] + bz4.y);
            float h1 = gate(acc[i][n][2] + bz4.z, acc[i][n][3] + bz4.w);
            hu[i][n] = pack2(h0, h1);
        }
    }
    __syncthreads();  // all z reads of s_x done -> safe to alias as s_h
    #pragma unroll
    for (int i = 0; i < 2; i++) {
        int j0 = (w * 2 + i) * 8 + quad * 2;
        #pragma unroll
        for (int n = 0; n < 2; n++)
            *(unsigned*)&s_h[(n * 16 + tloc) * 136 + j0] = hu[i][n];
    }
    __syncthreads();
    // ---- skip GEMM (2 mt/wave) + res GEMM (1 mt/wave), K=128, N=32 ----
    f32x4 sacc[2][2], racc[2];
    #pragma unroll
    for (int i = 0; i < 2; i++)
        #pragma unroll
        for (int n = 0; n < 2; n++) sacc[i][n] = (f32x4){0.f, 0.f, 0.f, 0.f};
    #pragma unroll
    for (int n = 0; n < 2; n++) racc[n] = (f32x4){0.f, 0.f, 0.f, 0.f};
    for (int ks = 0; ks < 4; ks++) {
        if (ks < 3) {
            #pragma unroll
            for (int i = 0; i < 2; i++)
                sa_n[i] = sap[((size_t)(ks + 1) * 16 + w * 2 + i) * 64 + l];
            ra_n = rap[((size_t)(ks + 1) * 8 + w) * 64 + l];
        }
        short8 b[2];
        int k0 = ks * 32 + quad * 8;
        #pragma unroll
        for (int n = 0; n < 2; n++)
            b[n] = *(const short8*)&s_h[(n * 16 + tloc) * 136 + k0];
        #pragma unroll
        for (int i = 0; i < 2; i++)
            #pragma unroll
            for (int n = 0; n < 2; n++) sacc[i][n] = MFMA(sa_c[i], b[n], sacc[i][n]);
        #pragma unroll
        for (int n = 0; n < 2; n++) racc[n] = MFMA(ra_c, b[n], racc[n]);
        #pragma unroll
        for (int i = 0; i < 2; i++) sa_c[i] = sa_n[i];
        ra_c = ra_n;
    }
    // ---- skip epilogue: bf16 RMW in [L][240] ----
    #pragma unroll
    for (int i = 0; i < 2; i++) {
        int m_base = (w * 2 + i) * 16 + quad * 4;
        if (m_base >= 240) continue;
        float4 sb4 = *(const float4*)(skbias + blk * 240 + m_base);
        #pragma unroll
        for (int n = 0; n < 2; n++) {
            int t = t0 + n * 16 + tloc;
            if (t >= L_LEN) continue;
            float x0 = sacc[i][n][0] + sb4.x;
            float x1 = sacc[i][n][1] + sb4.y;
            float x2 = sacc[i][n][2] + sb4.z;
            float x3 = sacc[i][n][3] + sb4.w;
            if (!first) {
                uint2 pv = skp[i][n];
                x0 += b16tof((u16)(pv.x & 0xFFFF));
                x1 += b16tof((u16)(pv.x >> 16));
                x2 += b16tof((u16)(pv.y & 0xFFFF));
                x3 += b16tof((u16)(pv.y >> 16));
            }
            uint2 ov;
            ov.x = pack2(x0, x1);
            ov.y = pack2(x2, x3);
            *(uint2*)(skipT + (size_t)t * 240 + m_base) = ov;
        }
    }
    // ---- res epilogue (uses prefetched rcur) ----
    {
        int m_base = w * 16 + quad * 4;
        if (m_base < 120) {
            float4 rb4 = *(const float4*)(resb + blk * 120 + m_base);
            #pragma unroll
            for (int n = 0; n < 2; n++) {
                int t = t0 + n * 16 + tloc;
                if (t >= L_LEN) continue;
                float4 cur = rcur[n];
                float4 o;
                o.x = cur.x + racc[n][0] + rb4.x;
                o.y = cur.y + racc[n][1] + rb4.y;
                o.z = cur.z + racc[n][2] + rb4.z;
                o.w = cur.w + racc[n][3] + rb4.w;
                *(float4*)(resT_out + (size_t)t * 120 + m_base) = o;
            }
        }
    }
}

// ================= head (MFMA, 512 thr) =================
__global__ __launch_bounds__(512, 4) void k_final(const u16* __restrict__ skipT,
        const u16* __restrict__ h1f, const u16* __restrict__ h2f,
        const float* __restrict__ h1_b, const float* __restrict__ h2_b,
        float* __restrict__ out) {
    __shared__ u16 s_m[64 * 264];
    const int tid = threadIdx.x, l = tid & 63, w = tid >> 6;  // w 0..7
    const int quad = l >> 4, tloc = l & 15;
    const int t0 = blockIdx.x * 64;
    const short8* ap1 = (const short8*)h1f;
    short8 a_cur[2], a_nxt[2];
    #pragma unroll
    for (int i = 0; i < 2; i++) a_cur[i] = ap1[(size_t)(w * 2 + i) * 64 + l];
    // stage relu(skip) from bf16
    for (int rr = 0; rr < 8; rr++) {
        int tt = w + 8 * rr;
        int tg = t0 + tt;
        uint2 v = make_uint2(0u, 0u);
        if (l < 60 && tg < L_LEN)
            v = *(const uint2*)(skipT + (size_t)tg * 240 + 4 * l);
        float x0 = fmaxf(b16tof((u16)(v.x & 0xFFFF)), 0.f);
        float x1 = fmaxf(b16tof((u16)(v.x >> 16)), 0.f);
        float x2 = fmaxf(b16tof((u16)(v.y & 0xFFFF)), 0.f);
        float x3 = fmaxf(b16tof((u16)(v.y >> 16)), 0.f);
        uint2 ov;
        ov.x = pack2(x0, x1);
        ov.y = pack2(x2, x3);
        *(uint2*)&s_m[tt * 264 + 4 * l] = ov;
    }
    __syncthreads();
    f32x4 acc[2][4];
    #pragma unroll
    for (int i = 0; i < 2; i++)
        #pragma unroll
        for (int n = 0; n < 4; n++) acc[i][n] = (f32x4){0.f, 0.f, 0.f, 0.f};
    for (int ks = 0; ks < 8; ks++) {
        if (ks < 7) {
            #pragma unroll
            for (int i = 0; i < 2; i++)
                a_nxt[i] = ap1[((size_t)(ks + 1) * 16 + w * 2 + i) * 64 + l];
        }
        short8 b[4];
        int k0 = ks * 32 + quad * 8;
        #pragma unroll
        for (int n = 0; n < 4; n++)
            b[n] = *(const short8*)&s_m[(n * 16 + tloc) * 264 + k0];
        #pragma unroll
        for (int i = 0; i < 2; i++)
            #pragma unroll
            for (int n = 0; n < 4; n++) acc[i][n] = MFMA(a_cur[i], b[n], acc[i][n]);
        #pragma unroll
        for (int i = 0; i < 2; i++) a_cur[i] = a_nxt[i];
    }
    unsigned ylo[2][4], yhi[2][4];
    #pragma unroll
    for (int i = 0; i < 2; i++) {
        int m_base = (w * 2 + i) * 16 + quad * 4;
        float4 b1 = *(const float4*)(h1_b + m_base);
        #pragma unroll
        for (int n = 0; n < 4; n++) {
            float y0 = fmaxf(acc[i][n][0] + b1.x, 0.f);
            float y1v = fmaxf(acc[i][n][1] + b1.y, 0.f);
            float y2 = fmaxf(acc[i][n][2] + b1.z, 0.f);
            float y3 = fmaxf(acc[i][n][3] + b1.w, 0.f);
            ylo[i][n] = pack2(y0, y1v);
            yhi[i][n] = pack2(y2, y3);
        }
    }
    const short8* ap2 = (const short8*)h2f;
    #pragma unroll
    for (int i = 0; i < 2; i++) a_cur[i] = ap2[(size_t)(w * 2 + i) * 64 + l];
    __syncthreads();
    #pragma unroll
    for (int i = 0; i < 2; i++) {
        int m_base = (w * 2 + i) * 16 + quad * 4;
        #pragma unroll
        for (int n = 0; n < 4; n++) {
            int t = n * 16 + tloc;
            *(unsigned*)&s_m[t * 264 + m_base]     = ylo[i][n];
            *(unsigned*)&s_m[t * 264 + m_base + 2] = yhi[i][n];
        }
    }
    __syncthreads();
    #pragma unroll
    for (int i = 0; i < 2; i++)
        #pragma unroll
        for (int n = 0; n < 4; n++) acc[i][n] = (f32x4){0.f, 0.f, 0.f, 0.f};
    for (int ks = 0; ks < 8; ks++) {
        if (ks < 7) {
            #pragma unroll
            for (int i = 0; i < 2; i++)
                a_nxt[i] = ap2[((size_t)(ks + 1) * 16 + w * 2 + i) * 64 + l];
        }
        short8 b[4];
        int k0 = ks * 32 + quad * 8;
        #pragma unroll
        for (int n = 0; n < 4; n++)
            b[n] = *(const short8*)&s_m[(n * 16 + tloc) * 264 + k0];
        #pragma unroll
        for (int i = 0; i < 2; i++)
            #pragma unroll
            for (int n = 0; n < 4; n++) acc[i][n] = MFMA(a_cur[i], b[n], acc[i][n]);
        #pragma unroll
        for (int i = 0; i < 2; i++) a_cur[i] = a_nxt[i];
    }
    #pragma unroll
    for (int i = 0; i < 2; i++) {
        int m_base = (w * 2 + i) * 16 + quad * 4;
        float4 b2 = *(const float4*)(h2_b + m_base);
        float bb[4] = {b2.x, b2.y, b2.z, b2.w};
        #pragma unroll
        for (int n = 0; n < 4; n++) {
            int t = t0 + n * 16 + tloc;
            if (t >= L_LEN) continue;
            #pragma unroll
            for (int r = 0; r < 4; r++)
                out[(size_t)(m_base + r) * L_LEN + t] = acc[i][n][r] + bb[r];
        }
    }
}

extern "C" void kernel_launch(void* const* d_in, const int* in_sizes, int n_in,
                              void* d_out, int out_size, void* d_ws, size_t ws_size,
                              hipStream_t stream) {
    const float* wav   = (const float*)d_in[0];
    const float* mel   = (const float*)d_in[1];
    const float* up_w  = (const float*)d_in[2];
    const float* up_b  = (const float*)d_in[3];
    const float* in_w  = (const float*)d_in[4];
    const float* in_b  = (const float*)d_in[5];
    const float* bc_w  = (const float*)d_in[6];
    const float* bc_b  = (const float*)d_in[7];
    const float* bq_w  = (const float*)d_in[8];
    const float* bq_b  = (const float*)d_in[9];
    const float* bs_w  = (const float*)d_in[10];
    const float* bs_b  = (const float*)d_in[11];
    const float* br_w  = (const float*)d_in[12];
    const float* br_b  = (const float*)d_in[13];
    const float* h1_w  = (const float*)d_in[14];
    const float* h1_b  = (const float*)d_in[15];
    const float* h2_w  = (const float*)d_in[16];
    const float* h2_b  = (const float*)d_in[17];

    char* wsb = (char*)d_ws;
    u16*   condT = (u16*)(wsb + O_CONDT);
    float* resA  = (float*)(wsb + O_RESA);
    float* resB  = (float*)(wsb + O_RESB);
    u16*   skipT = (u16*)(wsb + O_SKIP);
    u16*   zfrag = (u16*)(wsb + O_ZFRAG);
    u16*   skf   = (u16*)(wsb + O_SKF);
    u16*   rf    = (u16*)(wsb + O_RF);
    u16*   h1f   = (u16*)(wsb + O_H1F);
    u16*   h2f   = (u16*)(wsb + O_H2F);
    u16*   upf   = (u16*)(wsb + O_UPF);
    float* zb    = (float*)(wsb + O_ZB);
    float* skb   = (float*)(wsb + O_SKB);

    k_prep_zfrag <<<5120, 256, 0, stream>>>(bc_w, bq_w, zfrag);
    k_prep_skfrag<<<2048, 256, 0, stream>>>(bs_w, skf);
    k_prep_rfrag <<<1024, 256, 0, stream>>>(br_w, rf);
    k_prep_h1frag<<<256, 256, 0, stream>>>(h1_w, h1f);
    k_prep_h2frag<<<256, 256, 0, stream>>>(h2_w, h2f);
    k_prep_upfrag<<<25600, 256, 0, stream>>>(up_w, upf);
    k_prep_zbias <<<16, 256, 0, stream>>>(bc_b, bq_b, zb);
    k_prep_skbias<<<15, 256, 0, stream>>>(bs_b, skb);
    k_res_initT  <<<(L_LEN * RCH + 255) / 256, 256, 0, stream>>>(wav, in_w, in_b, resA);
    k_up<<<dim3(256, 3), 256, 0, stream>>>(mel, upf, up_b, condT);

    for (int i = 0; i < NBLK; i++) {
        int d = 1 << (i & 7);
        const float* rin = (i & 1) ? resB : resA;
        float* rout      = (i & 1) ? resA : resB;
        k_block<<<NT32, 512, 0, stream>>>(condT, rin, rout, skipT, zfrag, skf, rf,
                                          zb, skb, br_b, i, d, (i == 0) ? 1 : 0);
    }
    k_final<<<NT, 512, 0, stream>>>(skipT, h1f, h2f, h1_b, h2_b, (float*)d_out);
}